// Round 8
// baseline (36.476 us; speedup 1.0000x reference)
//
#include <hip/hip_runtime.h>
#include <hip/hip_bf16.h>
#include <math.h>

// B=2, L=5, C=32, H=48, W=176, NUM_ITER=1.
// Cuts: only i=0 slice matters (R1); conv = warped-half (per j) + ego-half (per b) (R1);
// conv+mlp on MFMA bf16 (R3). R8: back to 2-kernel split (R4 — gather phase needs TLP,
// MFMA phase needs ILP; separate kernels give each its own parallelism). k_fused:
// 512-thr blocks, oc-split wave pairs (2 waves/SIMD), double-buffered A prefetch,
// weights from pre-packed bf16 Wp (no per-block fp32 repack herd), no x0cl (skip from egocl).
#define BB 2
#define LL 5
#define CC 32
#define HH 48
#define WW 176
#define HWs (HH * WW)          // 8448
#define BL (BB * LL)           // 10

typedef __attribute__((ext_vector_type(8))) short bf16x8;
typedef __attribute__((ext_vector_type(4))) float f32x4;

__device__ __forceinline__ unsigned short f2bf(float v) {
    __hip_bfloat16 h = __float2bfloat16(v);   // RNE
    return *reinterpret_cast<unsigned short*>(&h);
}
__device__ __forceinline__ float bf2f(unsigned short u) {
    __hip_bfloat16 h = *reinterpret_cast<__hip_bfloat16*>(&u);
    return __bfloat162float(h);
}

// ---- bilinear weights/indices for grid_sample(align_corners=False, zeros pad) ----
__device__ __forceinline__ void bilin_weights(const float* __restrict__ Mp, int h, int w,
                                              int& o00, int& o10, int& o01, int& o11,
                                              float& a00, float& a10, float& a01, float& a11)
{
    float xs = (2.0f * (float)w + 1.0f) / (float)WW - 1.0f;
    float ys = (2.0f * (float)h + 1.0f) / (float)HH - 1.0f;
    float gx = Mp[0] * xs + Mp[1] * ys + Mp[2];
    float gy = Mp[3] * xs + Mp[4] * ys + Mp[5];
    float ix = ((gx + 1.0f) * (float)WW - 1.0f) * 0.5f;
    float iy = ((gy + 1.0f) * (float)HH - 1.0f) * 0.5f;
    float x0f = floorf(ix), y0f = floorf(iy);
    float wx = ix - x0f, wy = iy - y0f;
    float x1f = x0f + 1.0f, y1f = y0f + 1.0f;
    bool vx0 = (x0f >= 0.0f) && (x0f <= (float)(WW - 1));
    bool vx1 = (x1f >= 0.0f) && (x1f <= (float)(WW - 1));
    bool vy0 = (y0f >= 0.0f) && (y0f <= (float)(HH - 1));
    bool vy1 = (y1f >= 0.0f) && (y1f <= (float)(HH - 1));
    int xi0 = (int)fminf(fmaxf(x0f, 0.0f), (float)(WW - 1));
    int xi1 = (int)fminf(fmaxf(x1f, 0.0f), (float)(WW - 1));
    int yi0 = (int)fminf(fmaxf(y0f, 0.0f), (float)(HH - 1));
    int yi1 = (int)fminf(fmaxf(y1f, 0.0f), (float)(HH - 1));
    o00 = yi0 * WW + xi0;
    o10 = yi0 * WW + xi1;
    o01 = yi1 * WW + xi0;
    o11 = yi1 * WW + xi1;
    a00 = (vx0 && vy0) ? (1.0f - wx) * (1.0f - wy) : 0.0f;
    a10 = (vx1 && vy0) ? wx * (1.0f - wy) : 0.0f;
    a01 = (vx0 && vy1) ? (1.0f - wx) * wy : 0.0f;
    a11 = (vx1 && vy1) ? wx * wy : 0.0f;
}

// ---- K_prep: y<10: warp -> warpedcl bf16 CL + mask (cg==0);
//              y=10,11: ego copy -> egocl bf16 CL;
//              y=12: pack msg_w -> Wp [half][tap][oc][ic] bf16, mlp_w -> Wp2 [d][c] bf16
__global__ __launch_bounds__(256) void k_prep(const float* __restrict__ x,
                                              const float* __restrict__ M,
                                              const float* __restrict__ msg_w,
                                              const float* __restrict__ mlp_w,
                                              unsigned short* __restrict__ warpedcl,
                                              unsigned short* __restrict__ egocl,
                                              float* __restrict__ maskb,
                                              unsigned short* __restrict__ Wp,
                                              unsigned short* __restrict__ Wp2)
{
    int y = blockIdx.y;
    if (y < BL) {
        int pix = blockIdx.x * 256 + threadIdx.x;
        int cg  = blockIdx.z;
        int w = pix % WW, h = pix / WW;
        int b = y / LL, j = y % LL;
        const float* Mp = M + (size_t)(b * LL * LL + j) * 6;   // M[b][0][j]
        int o00, o10, o01, o11;
        float a00, a10, a01, a11;
        bilin_weights(Mp, h, w, o00, o10, o01, o11, a00, a10, a01, a11);
        if (cg == 0)
            maskb[(size_t)y * HWs + pix] = a00 + a10 + a01 + a11;
        const float* img = x + (size_t)y * CC * HWs + (size_t)cg * 8 * HWs;
        bf16x8 v8;
#pragma unroll
        for (int c = 0; c < 8; ++c) {
            const float* ip = img + (size_t)c * HWs;
            float v = a00 * ip[o00] + a10 * ip[o10] + a01 * ip[o01] + a11 * ip[o11];
            v8[c] = (short)f2bf(v);
        }
        *(bf16x8*)(warpedcl + ((size_t)y * HWs + pix) * CC + cg * 8) = v8;
    } else if (y < BL + BB) {
        int b = y - BL;
        int pix = blockIdx.x * 256 + threadIdx.x;
        int cg  = blockIdx.z;
        const float* img = x + (size_t)(b * LL) * CC * HWs + (size_t)cg * 8 * HWs;
        bf16x8 v8;
#pragma unroll
        for (int c = 0; c < 8; ++c)
            v8[c] = (short)f2bf(img[(size_t)c * HWs + pix]);
        *(bf16x8*)(egocl + ((size_t)b * HWs + pix) * CC + cg * 8) = v8;
    } else {
        int i = (blockIdx.z * gridDim.x + blockIdx.x) * 256 + threadIdx.x;
        if (i < 2 * 9 * 32 * 32) {
            int half = i / (9 * 32 * 32);
            int r    = i % (9 * 32 * 32);
            int tap  = r / (32 * 32);
            int r2   = r % (32 * 32);
            int oc   = r2 / 32;
            int ic   = r2 % 32;
            Wp[i] = f2bf(msg_w[(size_t)oc * 576 + (size_t)(half * 32 + ic) * 9 + tap]);
        } else if (i < 2 * 9 * 32 * 32 + 32 * 32) {
            int k = i - 2 * 9 * 32 * 32;
            Wp2[k] = f2bf(mlp_w[k]);     // [d][c] row-major
        }
    }
}

// ---- K_fused: 512 thr; wave pair (tw, nt): tile tw (16 px), oc-half nt.
//      conv (ego + 5j MFMA, A-prefetch dbuf) + bias + mask*max + skip + mlp MFMA ----
__global__ __launch_bounds__(512) void k_fused(const unsigned short* __restrict__ warpedcl,
                                               const unsigned short* __restrict__ egocl,
                                               const float* __restrict__ maskb,
                                               const unsigned short* __restrict__ Wp,
                                               const unsigned short* __restrict__ Wp2,
                                               const float* __restrict__ msg_b,
                                               const float* __restrict__ mlp_b,
                                               float* __restrict__ out)
{
    __shared__ float flds[64][36];   // stride 36 words -> 2-way bank alias (free)

    const int tid  = threadIdx.x;
    const int wv   = tid >> 6;       // 0..7
    const int lane = tid & 63;
    const int lo   = lane & 15;
    const int kblk = lane >> 4;
    const int nt   = wv >> 2;        // oc half (0/1)
    const int tw   = wv & 3;         // pixel sub-tile
    const int b    = blockIdx.y;
    const int p0   = blockIdx.x * 64 + tw * 16;
    const int pf   = p0 + lo;
    const int ph   = pf / WW, pw = pf % WW;

    // per-tap safe source pixel + validity
    int ps[9];
    unsigned vbits = 0;
#pragma unroll
    for (int tap = 0; tap < 9; ++tap) {
        int dy = tap / 3 - 1, dx = tap % 3 - 1;
        int hh = ph + dy, wq = pw + dx;
        bool valid = (hh >= 0) && (hh < HH) && (wq >= 0) && (wq < WW);
        ps[tap] = valid ? (pf + dy * WW + dx) : pf;
        vbits |= (valid ? 1u : 0u) << tap;
    }
    const bf16x8 zero = {0, 0, 0, 0, 0, 0, 0, 0};

    // B-fragments for this oc-half (warped half of the conv)
    bf16x8 Bw[9];
#pragma unroll
    for (int tap = 0; tap < 9; ++tap)
        Bw[tap] = *(const bf16x8*)(Wp + ((size_t)(tap * 32 + nt * 16 + lo)) * 32 + kblk * 8);

    // prefetch ego A-frags -> afA, j=0 A-frags -> afB (36 loads in flight)
    bf16x8 afA[9], afB[9];
    const unsigned short* Ae  = egocl + (size_t)b * HWs * CC;
    const unsigned short* Aw0 = warpedcl + (size_t)(b * LL) * HWs * CC;
#pragma unroll
    for (int tap = 0; tap < 9; ++tap)
        afA[tap] = *(const bf16x8*)(Ae + (size_t)ps[tap] * CC + kblk * 8);
#pragma unroll
    for (int tap = 0; tap < 9; ++tap)
        afB[tap] = *(const bf16x8*)(Aw0 + (size_t)ps[tap] * CC + kblk * 8);

    // ego half-conv (+ conv bias)
    f32x4 acce = {};
#pragma unroll
    for (int tap = 0; tap < 9; ++tap) {
        bf16x8 a = ((vbits >> tap) & 1) ? afA[tap] : zero;
        bf16x8 Be = *(const bf16x8*)(Wp + 9 * 32 * 32 + ((size_t)(tap * 32 + nt * 16 + lo)) * 32 + kblk * 8);
        acce = __builtin_amdgcn_mfma_f32_16x16x32_bf16(a, Be, acce, 0, 0, 0);
    }
    {
        float cb = msg_b[nt * 16 + lo];
#pragma unroll
        for (int r = 0; r < 4; ++r) acce[r] += cb;
    }

    // j loop: j even reads afB, odd reads afA; prefetch j+1 into the other
    f32x4 agg;
#pragma unroll
    for (int r = 0; r < 4; ++r) agg[r] = -INFINITY;

#pragma unroll
    for (int j = 0; j < LL; ++j) {
        bf16x8* cur = (j & 1) ? afA : afB;
        bf16x8* nxt = (j & 1) ? afB : afA;
        if (j < 4) {
            const unsigned short* Awn = warpedcl + (size_t)(b * LL + j + 1) * HWs * CC;
#pragma unroll
            for (int tap = 0; tap < 9; ++tap)
                nxt[tap] = *(const bf16x8*)(Awn + (size_t)ps[tap] * CC + kblk * 8);
        }
        f32x4 acc = {};
#pragma unroll
        for (int tap = 0; tap < 9; ++tap) {
            bf16x8 a = ((vbits >> tap) & 1) ? cur[tap] : zero;
            acc = __builtin_amdgcn_mfma_f32_16x16x32_bf16(a, Bw[tap], acc, 0, 0, 0);
        }
        float4 mk = *(const float4*)(maskb + (size_t)(b * LL + j) * HWs + p0 + kblk * 4);
        float mkr[4] = {mk.x, mk.y, mk.z, mk.w};
#pragma unroll
        for (int r = 0; r < 4; ++r)
            agg[r] = fmaxf(agg[r], (acc[r] + acce[r]) * mkr[r]);
    }

    // f = agg + skip(egocl bf16) -> LDS (full 32-c rows need both oc-halves -> barrier)
#pragma unroll
    for (int r = 0; r < 4; ++r) {
        int px = kblk * 4 + r;
        float skip = bf2f(egocl[((size_t)b * HWs + p0 + px) * CC + nt * 16 + lo]);
        flds[tw * 16 + px][nt * 16 + lo] = agg[r] + skip;
    }
    __syncthreads();

    // mlp MFMA: A = f[pix][c] (m=lo pixel of tile tw, k=c), B = Wp2[d][c] for this nt
    bf16x8 Afm;
#pragma unroll
    for (int e = 0; e < 8; ++e)
        Afm[e] = (short)f2bf(flds[tw * 16 + lo][kblk * 8 + e]);

    bf16x8 Bm = *(const bf16x8*)(Wp2 + (size_t)(nt * 16 + lo) * 32 + kblk * 8);
    f32x4 om = {};
    om = __builtin_amdgcn_mfma_f32_16x16x32_bf16(Afm, Bm, om, 0, 0, 0);
    float mb2 = mlp_b[nt * 16 + lo];
    int d = nt * 16 + lo;
    float4 o4 = make_float4(om[0] + mb2, om[1] + mb2, om[2] + mb2, om[3] + mb2);
    *(float4*)(out + ((size_t)(b * CC + d)) * HWs + p0 + kblk * 4) = o4;
}

extern "C" void kernel_launch(void* const* d_in, const int* in_sizes, int n_in,
                              void* d_out, int out_size, void* d_ws, size_t ws_size,
                              hipStream_t stream)
{
    (void)in_sizes; (void)n_in; (void)out_size; (void)ws_size;
    const float* x     = (const float*)d_in[0];
    // d_in[1] = record_len (unused by reference)
    const float* M     = (const float*)d_in[2];
    const float* msg_w = (const float*)d_in[3];
    const float* msg_b = (const float*)d_in[4];
    const float* mlp_w = (const float*)d_in[5];
    const float* mlp_b = (const float*)d_in[6];
    float* out = (float*)d_out;

    // workspace layout (all segments 16B-aligned)
    unsigned short* Wp       = (unsigned short*)d_ws;                    // 18432 bf16
    unsigned short* Wp2      = Wp + 2 * 9 * 32 * 32;                     // 1024 bf16
    unsigned short* warpedcl = Wp2 + 32 * 32;                            // BL*HW*C bf16
    unsigned short* egocl    = warpedcl + (size_t)BL * HWs * CC;         // BB*HW*C bf16
    float*          maskb    = (float*)(egocl + (size_t)BB * HWs * CC);  // BL*HW f32

    {
        dim3 g(HWs / 256, BL + BB + 1, 4);   // (33, 13, 4)
        k_prep<<<g, 256, 0, stream>>>(x, M, msg_w, mlp_w,
                                      warpedcl, egocl, maskb, Wp, Wp2);
    }
    {
        dim3 g(HWs / 64, BB);                // (132, 2) blocks of 512
        k_fused<<<g, 512, 0, stream>>>(warpedcl, egocl, maskb, Wp, Wp2,
                                       msg_b, mlp_b, out);
    }
}

// Round 9
// 29.652 us; speedup vs baseline: 1.2302x; 1.2302x over previous
//
#include <hip/hip_runtime.h>
#include <hip/hip_bf16.h>
#include <math.h>

// B=2, L=5, C=32, H=48, W=176, NUM_ITER=1.
// Cuts: only i=0 slice matters (R1); conv = warped-half (per j) + ego-half (per b) (R1);
// conv as tap-wise implicit GEMM on MFMA bf16 (R3); 2-kernel split: high-TLP gather prep
// + compact MFMA consumer (R4 — best measured; R5-R8 restructures all regressed).
// R9: R4 exactly, minus x0cl (skip-add reads egocl bf16 instead; R8 verified absmax).
#define BB 2
#define LL 5
#define CC 32
#define HH 48
#define WW 176
#define HWs (HH * WW)          // 8448
#define BL (BB * LL)           // 10

typedef __attribute__((ext_vector_type(8))) short bf16x8;
typedef __attribute__((ext_vector_type(4))) float f32x4;

__device__ __forceinline__ unsigned short f2bf(float v) {
    __hip_bfloat16 h = __float2bfloat16(v);   // RNE
    return *reinterpret_cast<unsigned short*>(&h);
}
__device__ __forceinline__ float bf2f(unsigned short u) {
    __hip_bfloat16 h = *reinterpret_cast<__hip_bfloat16*>(&u);
    return __bfloat162float(h);
}

// ---- bilinear weights/indices for grid_sample(align_corners=False, zeros pad) ----
__device__ __forceinline__ void bilin_weights(const float* __restrict__ Mp, int h, int w,
                                              int& o00, int& o10, int& o01, int& o11,
                                              float& a00, float& a10, float& a01, float& a11)
{
    float xs = (2.0f * (float)w + 1.0f) / (float)WW - 1.0f;
    float ys = (2.0f * (float)h + 1.0f) / (float)HH - 1.0f;
    float gx = Mp[0] * xs + Mp[1] * ys + Mp[2];
    float gy = Mp[3] * xs + Mp[4] * ys + Mp[5];
    float ix = ((gx + 1.0f) * (float)WW - 1.0f) * 0.5f;
    float iy = ((gy + 1.0f) * (float)HH - 1.0f) * 0.5f;
    float x0f = floorf(ix), y0f = floorf(iy);
    float wx = ix - x0f, wy = iy - y0f;
    float x1f = x0f + 1.0f, y1f = y0f + 1.0f;
    bool vx0 = (x0f >= 0.0f) && (x0f <= (float)(WW - 1));
    bool vx1 = (x1f >= 0.0f) && (x1f <= (float)(WW - 1));
    bool vy0 = (y0f >= 0.0f) && (y0f <= (float)(HH - 1));
    bool vy1 = (y1f >= 0.0f) && (y1f <= (float)(HH - 1));
    int xi0 = (int)fminf(fmaxf(x0f, 0.0f), (float)(WW - 1));
    int xi1 = (int)fminf(fmaxf(x1f, 0.0f), (float)(WW - 1));
    int yi0 = (int)fminf(fmaxf(y0f, 0.0f), (float)(HH - 1));
    int yi1 = (int)fminf(fmaxf(y1f, 0.0f), (float)(HH - 1));
    o00 = yi0 * WW + xi0;
    o10 = yi0 * WW + xi1;
    o01 = yi1 * WW + xi0;
    o11 = yi1 * WW + xi1;
    a00 = (vx0 && vy0) ? (1.0f - wx) * (1.0f - wy) : 0.0f;
    a10 = (vx1 && vy0) ? wx * (1.0f - wy) : 0.0f;
    a01 = (vx0 && vy1) ? (1.0f - wx) * wy : 0.0f;
    a11 = (vx1 && vy1) ? wx * wy : 0.0f;
}

// ---- K_prep: y<10: warp -> warpedcl (bf16 CL) + mask (z==0);
//              y=10,11: ego -> egocl (bf16 CL);
//              y=12: pack msg_w -> Wp [half][tap][oc][ic] bf16, mlp_w -> Wp2 [d][c] bf16
__global__ __launch_bounds__(256) void k_prep(const float* __restrict__ x,
                                              const float* __restrict__ M,
                                              const float* __restrict__ msg_w,
                                              const float* __restrict__ mlp_w,
                                              unsigned short* __restrict__ warpedcl,
                                              unsigned short* __restrict__ egocl,
                                              float* __restrict__ maskb,
                                              unsigned short* __restrict__ Wp,
                                              unsigned short* __restrict__ Wp2)
{
    int y = blockIdx.y;
    if (y < BL) {
        int pix = blockIdx.x * 256 + threadIdx.x;
        int cg  = blockIdx.z;
        int w = pix % WW, h = pix / WW;
        int b = y / LL, j = y % LL;
        const float* Mp = M + (size_t)(b * LL * LL + j) * 6;   // M[b][0][j]
        int o00, o10, o01, o11;
        float a00, a10, a01, a11;
        bilin_weights(Mp, h, w, o00, o10, o01, o11, a00, a10, a01, a11);
        if (cg == 0)
            maskb[(size_t)y * HWs + pix] = a00 + a10 + a01 + a11;
        const float* img = x + (size_t)y * CC * HWs + (size_t)cg * 8 * HWs;
        bf16x8 v8;
#pragma unroll
        for (int c = 0; c < 8; ++c) {
            const float* ip = img + (size_t)c * HWs;
            float v = a00 * ip[o00] + a10 * ip[o10] + a01 * ip[o01] + a11 * ip[o11];
            v8[c] = (short)f2bf(v);
        }
        *(bf16x8*)(warpedcl + ((size_t)y * HWs + pix) * CC + cg * 8) = v8;
    } else if (y < BL + BB) {
        int b = y - BL;
        int pix = blockIdx.x * 256 + threadIdx.x;
        int cg  = blockIdx.z;
        const float* img = x + (size_t)(b * LL) * CC * HWs + (size_t)cg * 8 * HWs;
        bf16x8 v8;
#pragma unroll
        for (int c = 0; c < 8; ++c)
            v8[c] = (short)f2bf(img[(size_t)c * HWs + pix]);
        *(bf16x8*)(egocl + ((size_t)b * HWs + pix) * CC + cg * 8) = v8;
    } else {
        int i = (blockIdx.z * gridDim.x + blockIdx.x) * 256 + threadIdx.x;
        if (i < 2 * 9 * 32 * 32) {
            int half = i / (9 * 32 * 32);
            int r    = i % (9 * 32 * 32);
            int tap  = r / (32 * 32);
            int r2   = r % (32 * 32);
            int oc   = r2 / 32;
            int ic   = r2 % 32;
            Wp[i] = f2bf(msg_w[(size_t)oc * 576 + (size_t)(half * 32 + ic) * 9 + tap]);
        } else if (i < 2 * 9 * 32 * 32 + 32 * 32) {
            int k = i - 2 * 9 * 32 * 32;
            Wp2[k] = f2bf(mlp_w[k]);     // [d][c] row-major, as stored
        }
    }
}

// ---- K_fused: per-wave 16-pixel tile (x2 m-tiles); 6 half-convs (MFMA) + bias +
//      mask*max + skip(egocl bf16) + mlp via second MFMA (same-wave LDS transpose) ----
__global__ __launch_bounds__(256) void k_fused(const unsigned short* __restrict__ warpedcl,
                                               const unsigned short* __restrict__ egocl,
                                               const float* __restrict__ maskb,
                                               const unsigned short* __restrict__ Wp,
                                               const unsigned short* __restrict__ Wp2,
                                               const float* __restrict__ msg_b,
                                               const float* __restrict__ mlp_b,
                                               float* __restrict__ out)
{
    __shared__ float fl[64][33];            // per-wave 16 rows; padded (2-way max conflicts)
    int wv   = threadIdx.x >> 6;
    int lane = threadIdx.x & 63;
    int lo   = lane & 15;
    int kblk = lane >> 4;
    int b    = blockIdx.y;
    int p0   = blockIdx.x * 64 + wv * 16;   // wave's 16 pixels
    int pf   = p0 + lo;
    int ph   = pf / WW, pw = pf % WW;

    // hoist tap addressing: safe pixel index + validity bit per tap
    int ps[9];
    unsigned vbits = 0;
#pragma unroll
    for (int tap = 0; tap < 9; ++tap) {
        int dy = tap / 3 - 1, dx = tap % 3 - 1;
        int hh = ph + dy, wwp = pw + dx;
        bool valid = (hh >= 0) && (hh < HH) && (wwp >= 0) && (wwp < WW);
        ps[tap] = valid ? (pf + dy * WW + dx) : pf;
        vbits |= (valid ? 1u : 0u) << tap;
    }
    const bf16x8 zero = {0, 0, 0, 0, 0, 0, 0, 0};

    // preload warped-half B fragments (reused across 5 j)
    bf16x8 Bw[9][2];
#pragma unroll
    for (int tap = 0; tap < 9; ++tap)
#pragma unroll
        for (int nt = 0; nt < 2; ++nt)
            Bw[tap][nt] = *(const bf16x8*)(Wp + ((size_t)(tap * 32 + nt * 16 + lo) * 32 + kblk * 8));

    // ego half-conv (+ conv bias folded in)
    f32x4 acce[2] = {};
    {
        const unsigned short* Ae = egocl + (size_t)b * HWs * CC;
#pragma unroll
        for (int tap = 0; tap < 9; ++tap) {
            bf16x8 Af = *(const bf16x8*)(Ae + (size_t)ps[tap] * CC + kblk * 8);
            if (!((vbits >> tap) & 1)) Af = zero;
#pragma unroll
            for (int nt = 0; nt < 2; ++nt) {
                bf16x8 Bf = *(const bf16x8*)(Wp + 9 * 32 * 32 + ((size_t)(tap * 32 + nt * 16 + lo) * 32 + kblk * 8));
                acce[nt] = __builtin_amdgcn_mfma_f32_16x16x32_bf16(Af, Bf, acce[nt], 0, 0, 0);
            }
        }
        float b0 = msg_b[lo], b1 = msg_b[16 + lo];
#pragma unroll
        for (int r = 0; r < 4; ++r) { acce[0][r] += b0; acce[1][r] += b1; }
    }

    // j-loop: warped half-conv, add ego+bias, mask, running max
    f32x4 agg[2];
#pragma unroll
    for (int r = 0; r < 4; ++r) { agg[0][r] = -INFINITY; agg[1][r] = -INFINITY; }

    for (int j = 0; j < LL; ++j) {
        const unsigned short* Aw = warpedcl + (size_t)(b * LL + j) * HWs * CC;
        f32x4 acc[2] = {};
#pragma unroll
        for (int tap = 0; tap < 9; ++tap) {
            bf16x8 Af = *(const bf16x8*)(Aw + (size_t)ps[tap] * CC + kblk * 8);
            if (!((vbits >> tap) & 1)) Af = zero;
#pragma unroll
            for (int nt = 0; nt < 2; ++nt)
                acc[nt] = __builtin_amdgcn_mfma_f32_16x16x32_bf16(Af, Bw[tap][nt], acc[nt], 0, 0, 0);
        }
        float4 mk = *(const float4*)(maskb + (size_t)(b * LL + j) * HWs + p0 + kblk * 4);
        float mkr[4] = {mk.x, mk.y, mk.z, mk.w};
#pragma unroll
        for (int nt = 0; nt < 2; ++nt)
#pragma unroll
            for (int r = 0; r < 4; ++r)
                agg[nt][r] = fmaxf(agg[nt][r], (acc[nt][r] + acce[nt][r]) * mkr[r]);
    }

    // f = x0 + agg -> LDS transpose (D-layout rows: pixel = kblk*4+r, col c = nt*16+lo)
#pragma unroll
    for (int nt = 0; nt < 2; ++nt)
#pragma unroll
        for (int r = 0; r < 4; ++r) {
            int pixl = kblk * 4 + r;
            float skip = bf2f(egocl[((size_t)b * HWs + p0 + pixl) * CC + nt * 16 + lo]);
            float f = agg[nt][r] + skip;
            fl[wv * 16 + pixl][nt * 16 + lo] = f;
        }
    // same-wave LDS read-back (compiler inserts lgkmcnt; no cross-wave sharing)

    // mlp: A = f[pix][c] (m=lo pixel, k=c), B = Wp2[d][c] (n=d, k=c)
    bf16x8 Afm;
#pragma unroll
    for (int e = 0; e < 8; ++e)
        Afm[e] = (short)f2bf(fl[wv * 16 + lo][kblk * 8 + e]);

#pragma unroll
    for (int nt2 = 0; nt2 < 2; ++nt2) {
        bf16x8 Bm = *(const bf16x8*)(Wp2 + ((size_t)(nt2 * 16 + lo) * 32 + kblk * 8));
        f32x4 om = {};
        om = __builtin_amdgcn_mfma_f32_16x16x32_bf16(Afm, Bm, om, 0, 0, 0);
        float mb2 = mlp_b[nt2 * 16 + lo];
        int d = nt2 * 16 + lo;
#pragma unroll
        for (int r = 0; r < 4; ++r)
            out[((size_t)b * CC + d) * HWs + p0 + kblk * 4 + r] = om[r] + mb2;
    }
}

extern "C" void kernel_launch(void* const* d_in, const int* in_sizes, int n_in,
                              void* d_out, int out_size, void* d_ws, size_t ws_size,
                              hipStream_t stream)
{
    (void)in_sizes; (void)n_in; (void)out_size; (void)ws_size;
    const float* x     = (const float*)d_in[0];
    // d_in[1] = record_len (unused by reference)
    const float* M     = (const float*)d_in[2];
    const float* msg_w = (const float*)d_in[3];
    const float* msg_b = (const float*)d_in[4];
    const float* mlp_w = (const float*)d_in[5];
    const float* mlp_b = (const float*)d_in[6];
    float* out = (float*)d_out;

    // workspace layout (all segments 16B-aligned)
    unsigned short* Wp       = (unsigned short*)d_ws;                    // 18432 bf16
    unsigned short* Wp2      = Wp + 2 * 9 * 32 * 32;                     // 1024 bf16
    unsigned short* warpedcl = Wp2 + 32 * 32;                            // BL*HW*C bf16
    unsigned short* egocl    = warpedcl + (size_t)BL * HWs * CC;         // BB*HW*C bf16
    float*          maskb    = (float*)(egocl + (size_t)BB * HWs * CC);  // BL*HW f32

    {
        dim3 g(HWs / 256, BL + BB + 1, 4);   // (33, 13, 4)
        k_prep<<<g, 256, 0, stream>>>(x, M, msg_w, mlp_w,
                                      warpedcl, egocl, maskb, Wp, Wp2);
    }
    {
        dim3 g(HWs / 64, BB);                // (132, 2)
        k_fused<<<g, 256, 0, stream>>>(warpedcl, egocl, maskb, Wp, Wp2,
                                       msg_b, mlp_b, out);
    }
}

// Round 10
// 27.369 us; speedup vs baseline: 1.3328x; 1.0834x over previous
//
#include <hip/hip_runtime.h>
#include <hip/hip_bf16.h>
#include <math.h>

// B=2, L=5, C=32, H=48, W=176, NUM_ITER=1.
// Cuts: only i=0 slice matters (R1); conv = warped-half (per j) + ego-half (per b) (R1);
// conv as tap-wise implicit GEMM on MFMA bf16 (R3); 2-kernel split frozen (R4/R9 best).
// R10: k_fused stages weights in LDS once/block (kills 4x per-wave L2 re-reads) +
// 3-buffer rolling A-frag prefetch (1 wave/SIMD -> ILP must hide L2 latency);
// k_prep pairs x-adjacent taps into float2 loads (32 -> 16 gather instrs).
#define BB 2
#define LL 5
#define CC 32
#define HH 48
#define WW 176
#define HWs (HH * WW)          // 8448
#define BL (BB * LL)           // 10
#define WROW 36                // padded LDS weight row stride (ushorts; 72B, 8B-aligned)

typedef __attribute__((ext_vector_type(8))) short bf16x8;
typedef __attribute__((ext_vector_type(4))) float f32x4;

__device__ __forceinline__ unsigned short f2bf(float v) {
    __hip_bfloat16 h = __float2bfloat16(v);   // RNE
    return *reinterpret_cast<unsigned short*>(&h);
}
__device__ __forceinline__ float bf2f(unsigned short u) {
    __hip_bfloat16 h = *reinterpret_cast<__hip_bfloat16*>(&u);
    return __bfloat162float(h);
}

// ---- K_prep: y<10: warp -> warpedcl (bf16 CL) + mask (z==0);
//              y=10,11: ego -> egocl (bf16 CL);
//              y=12: pack msg_w -> Wp [half][tap][oc][ic] bf16, mlp_w -> Wp2 [d][c] bf16
__global__ __launch_bounds__(256) void k_prep(const float* __restrict__ x,
                                              const float* __restrict__ M,
                                              const float* __restrict__ msg_w,
                                              const float* __restrict__ mlp_w,
                                              unsigned short* __restrict__ warpedcl,
                                              unsigned short* __restrict__ egocl,
                                              float* __restrict__ maskb,
                                              unsigned short* __restrict__ Wp,
                                              unsigned short* __restrict__ Wp2)
{
    int y = blockIdx.y;
    if (y < BL) {
        int pix = blockIdx.x * 256 + threadIdx.x;
        int cg  = blockIdx.z;
        int w = pix % WW, h = pix / WW;
        int b = y / LL, j = y % LL;
        const float* Mp = M + (size_t)(b * LL * LL + j) * 6;   // M[b][0][j]

        float xs = (2.0f * (float)w + 1.0f) / (float)WW - 1.0f;
        float ys = (2.0f * (float)h + 1.0f) / (float)HH - 1.0f;
        float gx = Mp[0] * xs + Mp[1] * ys + Mp[2];
        float gy = Mp[3] * xs + Mp[4] * ys + Mp[5];
        float ix = ((gx + 1.0f) * (float)WW - 1.0f) * 0.5f;
        float iy = ((gy + 1.0f) * (float)HH - 1.0f) * 0.5f;
        float x0f = floorf(ix), y0f = floorf(iy);
        float wx = ix - x0f, wy = iy - y0f;
        float x1f = x0f + 1.0f, y1f = y0f + 1.0f;
        bool vx0 = (x0f >= 0.0f) && (x0f <= (float)(WW - 1));
        bool vx1 = (x1f >= 0.0f) && (x1f <= (float)(WW - 1));
        bool vy0 = (y0f >= 0.0f) && (y0f <= (float)(HH - 1));
        bool vy1 = (y1f >= 0.0f) && (y1f <= (float)(HH - 1));
        int xi0 = (int)fminf(fmaxf(x0f, 0.0f), (float)(WW - 1));
        int yi0 = (int)fminf(fmaxf(y0f, 0.0f), (float)(HH - 1));
        int yi1 = (int)fminf(fmaxf(y1f, 0.0f), (float)(HH - 1));
        float a00 = (vx0 && vy0) ? (1.0f - wx) * (1.0f - wy) : 0.0f;
        float a10 = (vx1 && vy0) ? wx * (1.0f - wy) : 0.0f;
        float a01 = (vx0 && vy1) ? (1.0f - wx) * wy : 0.0f;
        float a11 = (vx1 && vy1) ? wx * wy : 0.0f;

        if (cg == 0)
            maskb[(size_t)y * HWs + pix] = a00 + a10 + a01 + a11;

        // x-adjacency: xi1 == xi0+1 iff x0f>=0 && x1f<=W-1; otherwise xi1==xi0 and the
        // invalid side's weight is 0, so one scalar serves both taps (bit-exact).
        bool adjx = (x0f >= 0.0f) && (x0f <= (float)(WW - 2));
        int oL0 = yi0 * WW + xi0;
        int oL1 = yi1 * WW + xi0;

        const float* img = x + (size_t)y * CC * HWs + (size_t)cg * 8 * HWs;
        bf16x8 v8;
#pragma unroll
        for (int c = 0; c < 8; ++c) {
            const float* q = img + (size_t)c * HWs;
            float v00, v10, v01, v11;
            if (adjx) {
                float2 u0 = *(const float2*)(q + oL0);
                float2 u1 = *(const float2*)(q + oL1);
                v00 = u0.x; v10 = u0.y; v01 = u1.x; v11 = u1.y;
            } else {
                v00 = v10 = q[oL0];
                v01 = v11 = q[oL1];
            }
            float v = a00 * v00 + a10 * v10 + a01 * v01 + a11 * v11;
            v8[c] = (short)f2bf(v);
        }
        *(bf16x8*)(warpedcl + ((size_t)y * HWs + pix) * CC + cg * 8) = v8;
    } else if (y < BL + BB) {
        int b = y - BL;
        int pix = blockIdx.x * 256 + threadIdx.x;
        int cg  = blockIdx.z;
        const float* img = x + (size_t)(b * LL) * CC * HWs + (size_t)cg * 8 * HWs;
        bf16x8 v8;
#pragma unroll
        for (int c = 0; c < 8; ++c)
            v8[c] = (short)f2bf(img[(size_t)c * HWs + pix]);
        *(bf16x8*)(egocl + ((size_t)b * HWs + pix) * CC + cg * 8) = v8;
    } else {
        int i = (blockIdx.z * gridDim.x + blockIdx.x) * 256 + threadIdx.x;
        if (i < 2 * 9 * 32 * 32) {
            int half = i / (9 * 32 * 32);
            int r    = i % (9 * 32 * 32);
            int tap  = r / (32 * 32);
            int r2   = r % (32 * 32);
            int oc   = r2 / 32;
            int ic   = r2 % 32;
            Wp[i] = f2bf(msg_w[(size_t)oc * 576 + (size_t)(half * 32 + ic) * 9 + tap]);
        } else if (i < 2 * 9 * 32 * 32 + 32 * 32) {
            int k = i - 2 * 9 * 32 * 32;
            Wp2[k] = f2bf(mlp_w[k]);     // [d][c] row-major, as stored
        }
    }
}

// read one B-fragment (16 bf16-bytes worth: 8 elems) from padded LDS weight array
__device__ __forceinline__ bf16x8 ldfrag(const unsigned short* __restrict__ wl,
                                         int row, int kblk)
{
    const unsigned short* p = wl + row * WROW + kblk * 8;   // 8B-aligned
    ushort4 u0 = *(const ushort4*)(p);
    ushort4 u1 = *(const ushort4*)(p + 4);
    bf16x8 r;
    r[0] = (short)u0.x; r[1] = (short)u0.y; r[2] = (short)u0.z; r[3] = (short)u0.w;
    r[4] = (short)u1.x; r[5] = (short)u1.y; r[6] = (short)u1.z; r[7] = (short)u1.w;
    return r;
}

// ---- K_fused: per-wave 16-pixel tile; weights LDS-staged once/block; rolling
//      A-prefetch; 6 half-convs + bias + mask*max + skip + mlp MFMA ----
__global__ __launch_bounds__(256) void k_fused(const unsigned short* __restrict__ warpedcl,
                                               const unsigned short* __restrict__ egocl,
                                               const float* __restrict__ maskb,
                                               const unsigned short* __restrict__ Wp,
                                               const unsigned short* __restrict__ Wp2,
                                               const float* __restrict__ msg_b,
                                               const float* __restrict__ mlp_b,
                                               float* __restrict__ out)
{
    __shared__ unsigned short wlds[608 * WROW];   // 43,776 B: rows 0..575 msg, 576..607 mlp
    __shared__ float fl[64][33];                  //  8,448 B

    const int tid  = threadIdx.x;
    const int wv   = tid >> 6;
    const int lane = tid & 63;
    const int lo   = lane & 15;
    const int kblk = lane >> 4;
    const int b    = blockIdx.y;
    const int p0   = blockIdx.x * 64 + wv * 16;
    const int pf   = p0 + lo;
    const int ph   = pf / WW, pw = pf % WW;

    // ---- stage Wp (18432) + Wp2 (1024, contiguous after Wp) into padded LDS ----
    // 19456 ushorts = 4864 quads = 19 exact iterations of 256 threads.
#pragma unroll
    for (int k = 0; k < 19; ++k) {
        int g = k * 256 + tid;
        ushort4 u = *(const ushort4*)(Wp + 4 * g);       // coalesced 8B global
        int row = g >> 3, col = (g & 7) * 4;
        *(ushort4*)(wlds + row * WROW + col) = u;        // 8B-aligned ds_write
    }

    // per-tap safe source pixel + validity (overlaps with staging)
    int ps[9];
    unsigned vbits = 0;
#pragma unroll
    for (int tap = 0; tap < 9; ++tap) {
        int dy = tap / 3 - 1, dx = tap % 3 - 1;
        int hh = ph + dy, wwp = pw + dx;
        bool valid = (hh >= 0) && (hh < HH) && (wwp >= 0) && (wwp < WW);
        ps[tap] = valid ? (pf + dy * WW + dx) : pf;
        vbits |= (valid ? 1u : 0u) << tap;
    }
    const bf16x8 zero = {0, 0, 0, 0, 0, 0, 0, 0};

    // issue ego A-frags + all masks early (fly under the barrier)
    bf16x8 afe[9];
    const unsigned short* Ae = egocl + (size_t)b * HWs * CC;
#pragma unroll
    for (int tap = 0; tap < 9; ++tap)
        afe[tap] = *(const bf16x8*)(Ae + (size_t)ps[tap] * CC + kblk * 8);
    float4 mks[LL];
#pragma unroll
    for (int j = 0; j < LL; ++j)
        mks[j] = *(const float4*)(maskb + (size_t)(b * LL + j) * HWs + p0 + kblk * 4);

    __syncthreads();

    // B-frags for warped half from LDS (kept in regs across all 5 j)
    bf16x8 Bw[9][2];
#pragma unroll
    for (int tap = 0; tap < 9; ++tap)
#pragma unroll
        for (int nt = 0; nt < 2; ++nt)
            Bw[tap][nt] = ldfrag(wlds, tap * 32 + nt * 16 + lo, kblk);

    // ego half-conv (+ conv bias); ego B-frags read from LDS on the fly
    f32x4 acce[2] = {};
#pragma unroll
    for (int tap = 0; tap < 9; ++tap) {
        bf16x8 a = ((vbits >> tap) & 1) ? afe[tap] : zero;
#pragma unroll
        for (int nt = 0; nt < 2; ++nt) {
            bf16x8 Be = ldfrag(wlds, 288 + tap * 32 + nt * 16 + lo, kblk);
            acce[nt] = __builtin_amdgcn_mfma_f32_16x16x32_bf16(a, Be, acce[nt], 0, 0, 0);
        }
    }
    {
        float b0 = msg_b[lo], b1 = msg_b[16 + lo];
#pragma unroll
        for (int r = 0; r < 4; ++r) { acce[0][r] += b0; acce[1][r] += b1; }
    }

    // rolling 3-buffer A-prefetch over j (full unroll -> static indices)
    bf16x8 afw[3][9];
#pragma unroll
    for (int jj = 0; jj < 2; ++jj) {
        const unsigned short* Aw = warpedcl + (size_t)(b * LL + jj) * HWs * CC;
#pragma unroll
        for (int tap = 0; tap < 9; ++tap)
            afw[jj][tap] = *(const bf16x8*)(Aw + (size_t)ps[tap] * CC + kblk * 8);
    }

    f32x4 agg[2];
#pragma unroll
    for (int r = 0; r < 4; ++r) { agg[0][r] = -INFINITY; agg[1][r] = -INFINITY; }

#pragma unroll
    for (int j = 0; j < LL; ++j) {
        if (j + 2 < LL) {
            const unsigned short* Aw = warpedcl + (size_t)(b * LL + j + 2) * HWs * CC;
#pragma unroll
            for (int tap = 0; tap < 9; ++tap)
                afw[(j + 2) % 3][tap] = *(const bf16x8*)(Aw + (size_t)ps[tap] * CC + kblk * 8);
        }
        f32x4 acc[2] = {};
#pragma unroll
        for (int tap = 0; tap < 9; ++tap) {
            bf16x8 a = ((vbits >> tap) & 1) ? afw[j % 3][tap] : zero;
#pragma unroll
            for (int nt = 0; nt < 2; ++nt)
                acc[nt] = __builtin_amdgcn_mfma_f32_16x16x32_bf16(a, Bw[tap][nt], acc[nt], 0, 0, 0);
        }
        float mkr[4] = {mks[j].x, mks[j].y, mks[j].z, mks[j].w};
#pragma unroll
        for (int nt = 0; nt < 2; ++nt)
#pragma unroll
            for (int r = 0; r < 4; ++r)
                agg[nt][r] = fmaxf(agg[nt][r], (acc[nt][r] + acce[nt][r]) * mkr[r]);
    }

    // f = agg + skip(egocl bf16) -> per-wave LDS transpose -> mlp MFMA
#pragma unroll
    for (int nt = 0; nt < 2; ++nt)
#pragma unroll
        for (int r = 0; r < 4; ++r) {
            int pixl = kblk * 4 + r;
            float skip = bf2f(egocl[((size_t)b * HWs + p0 + pixl) * CC + nt * 16 + lo]);
            fl[wv * 16 + pixl][nt * 16 + lo] = agg[nt][r] + skip;
        }
    // same-wave LDS read-back (lgkmcnt ordering; no cross-wave sharing)
    bf16x8 Afm;
#pragma unroll
    for (int e = 0; e < 8; ++e)
        Afm[e] = (short)f2bf(fl[wv * 16 + lo][kblk * 8 + e]);

#pragma unroll
    for (int nt2 = 0; nt2 < 2; ++nt2) {
        bf16x8 Bm = ldfrag(wlds, 576 + nt2 * 16 + lo, kblk);
        f32x4 om = {};
        om = __builtin_amdgcn_mfma_f32_16x16x32_bf16(Afm, Bm, om, 0, 0, 0);
        float mb2 = mlp_b[nt2 * 16 + lo];
        int d = nt2 * 16 + lo;
#pragma unroll
        for (int r = 0; r < 4; ++r)
            out[((size_t)b * CC + d) * HWs + p0 + kblk * 4 + r] = om[r] + mb2;
    }
}

extern "C" void kernel_launch(void* const* d_in, const int* in_sizes, int n_in,
                              void* d_out, int out_size, void* d_ws, size_t ws_size,
                              hipStream_t stream)
{
    (void)in_sizes; (void)n_in; (void)out_size; (void)ws_size;
    const float* x     = (const float*)d_in[0];
    // d_in[1] = record_len (unused by reference)
    const float* M     = (const float*)d_in[2];
    const float* msg_w = (const float*)d_in[3];
    const float* msg_b = (const float*)d_in[4];
    const float* mlp_w = (const float*)d_in[5];
    const float* mlp_b = (const float*)d_in[6];
    float* out = (float*)d_out;

    // workspace layout (all segments 16B-aligned; Wp2 contiguous after Wp — k_fused
    // stages both with one linear sweep)
    unsigned short* Wp       = (unsigned short*)d_ws;                    // 18432 bf16
    unsigned short* Wp2      = Wp + 2 * 9 * 32 * 32;                     // 1024 bf16
    unsigned short* warpedcl = Wp2 + 32 * 32;                            // BL*HW*C bf16
    unsigned short* egocl    = warpedcl + (size_t)BL * HWs * CC;         // BB*HW*C bf16
    float*          maskb    = (float*)(egocl + (size_t)BB * HWs * CC);  // BL*HW f32

    {
        dim3 g(HWs / 256, BL + BB + 1, 4);   // (33, 13, 4)
        k_prep<<<g, 256, 0, stream>>>(x, M, msg_w, mlp_w,
                                      warpedcl, egocl, maskb, Wp, Wp2);
    }
    {
        dim3 g(HWs / 64, BB);                // (132, 2)
        k_fused<<<g, 256, 0, stream>>>(warpedcl, egocl, maskb, Wp, Wp2,
                                       msg_b, mlp_b, out);
    }
}

// Round 11
// 26.979 us; speedup vs baseline: 1.3520x; 1.0144x over previous
//
#include <hip/hip_runtime.h>
#include <hip/hip_bf16.h>
#include <math.h>

// B=2, L=5, C=32, H=48, W=176, NUM_ITER=1.
// Cuts: only i=0 slice matters (R1); conv = warped-half (per j) + ego-half (per b) (R1);
// conv as tap-wise implicit GEMM on MFMA bf16 (R3); 2-kernel split frozen (R4/R9/R10).
// R10: LDS-staged weights + rolling A-prefetch in k_fused; paired-tap float2 gathers.
// R11: k_prep XCD-locality work mapping (T1): flat 1D grid, XCD r = id%8 owns warp
// image y=r (132 blocks each, r=0..7); leftover 660 blocks (images 8,9 + ego + pack)
// assigned contiguously. Kills ~8x cross-XCD L2 duplication of the source images.
#define BB 2
#define LL 5
#define CC 32
#define HH 48
#define WW 176
#define HWs (HH * WW)          // 8448
#define BL (BB * LL)           // 10
#define WROW 36                // padded LDS weight row stride (ushorts; 72B, 8B-aligned)

typedef __attribute__((ext_vector_type(8))) short bf16x8;
typedef __attribute__((ext_vector_type(4))) float f32x4;

__device__ __forceinline__ unsigned short f2bf(float v) {
    __hip_bfloat16 h = __float2bfloat16(v);   // RNE
    return *reinterpret_cast<unsigned short*>(&h);
}
__device__ __forceinline__ float bf2f(unsigned short u) {
    __hip_bfloat16 h = *reinterpret_cast<__hip_bfloat16*>(&u);
    return __bfloat162float(h);
}

// ---- K_prep (flat 1D grid, 1716 blocks): XCD-residue work mapping.
//   id%8 == r, q = id>>3:
//     q < 132          -> warp image y = r            (XCD-local source image)
//     q >= 132         -> leftover lid = leftoff(r)+(q-132): images 8,9; ego 10,11; pack 12
__global__ __launch_bounds__(256) void k_prep(const float* __restrict__ x,
                                              const float* __restrict__ M,
                                              const float* __restrict__ msg_w,
                                              const float* __restrict__ mlp_w,
                                              unsigned short* __restrict__ warpedcl,
                                              unsigned short* __restrict__ egocl,
                                              float* __restrict__ maskb,
                                              unsigned short* __restrict__ Wp,
                                              unsigned short* __restrict__ Wp2)
{
    int id = blockIdx.x;
    int r  = id & 7, q = id >> 3;
    int y, unit;
    if (q < 132) {
        y = r; unit = q;
    } else {
        // leftover pool: r<4 contributes 83 blocks (q=132..214), r>=4 contributes 82
        int leftoff = (r < 4) ? r * 83 : 332 + (r - 4) * 82;
        int lid = leftoff + (q - 132);     // 0..659
        y = 8 + lid / 132;                 // 8..12
        unit = lid % 132;
    }
    int xb = unit % 33;                    // 33 x-blocks of 256 pixels
    int cg = unit / 33;                    // 0..3 channel groups

    if (y < BL) {
        int pix = xb * 256 + threadIdx.x;
        int w = pix % WW, h = pix / WW;
        int b = y / LL, j = y % LL;
        const float* Mp = M + (size_t)(b * LL * LL + j) * 6;   // M[b][0][j]

        float xs = (2.0f * (float)w + 1.0f) / (float)WW - 1.0f;
        float ys = (2.0f * (float)h + 1.0f) / (float)HH - 1.0f;
        float gx = Mp[0] * xs + Mp[1] * ys + Mp[2];
        float gy = Mp[3] * xs + Mp[4] * ys + Mp[5];
        float ix = ((gx + 1.0f) * (float)WW - 1.0f) * 0.5f;
        float iy = ((gy + 1.0f) * (float)HH - 1.0f) * 0.5f;
        float x0f = floorf(ix), y0f = floorf(iy);
        float wx = ix - x0f, wy = iy - y0f;
        float x1f = x0f + 1.0f, y1f = y0f + 1.0f;
        bool vx0 = (x0f >= 0.0f) && (x0f <= (float)(WW - 1));
        bool vx1 = (x1f >= 0.0f) && (x1f <= (float)(WW - 1));
        bool vy0 = (y0f >= 0.0f) && (y0f <= (float)(HH - 1));
        bool vy1 = (y1f >= 0.0f) && (y1f <= (float)(HH - 1));
        int xi0 = (int)fminf(fmaxf(x0f, 0.0f), (float)(WW - 1));
        int yi0 = (int)fminf(fmaxf(y0f, 0.0f), (float)(HH - 1));
        int yi1 = (int)fminf(fmaxf(y1f, 0.0f), (float)(HH - 1));
        float a00 = (vx0 && vy0) ? (1.0f - wx) * (1.0f - wy) : 0.0f;
        float a10 = (vx1 && vy0) ? wx * (1.0f - wy) : 0.0f;
        float a01 = (vx0 && vy1) ? (1.0f - wx) * wy : 0.0f;
        float a11 = (vx1 && vy1) ? wx * wy : 0.0f;

        if (cg == 0)
            maskb[(size_t)y * HWs + pix] = a00 + a10 + a01 + a11;

        // x-adjacency: xi1 == xi0+1 iff x0f>=0 && x1f<=W-1; otherwise xi1==xi0 and the
        // invalid side's weight is 0, so one scalar serves both taps (bit-exact).
        bool adjx = (x0f >= 0.0f) && (x0f <= (float)(WW - 2));
        int oL0 = yi0 * WW + xi0;
        int oL1 = yi1 * WW + xi0;

        const float* img = x + (size_t)y * CC * HWs + (size_t)cg * 8 * HWs;
        bf16x8 v8;
#pragma unroll
        for (int c = 0; c < 8; ++c) {
            const float* qp = img + (size_t)c * HWs;
            float v00, v10, v01, v11;
            if (adjx) {
                float2 u0 = *(const float2*)(qp + oL0);
                float2 u1 = *(const float2*)(qp + oL1);
                v00 = u0.x; v10 = u0.y; v01 = u1.x; v11 = u1.y;
            } else {
                v00 = v10 = qp[oL0];
                v01 = v11 = qp[oL1];
            }
            float v = a00 * v00 + a10 * v10 + a01 * v01 + a11 * v11;
            v8[c] = (short)f2bf(v);
        }
        *(bf16x8*)(warpedcl + ((size_t)y * HWs + pix) * CC + cg * 8) = v8;
    } else if (y < BL + BB) {
        int b = y - BL;
        int pix = xb * 256 + threadIdx.x;
        const float* img = x + (size_t)(b * LL) * CC * HWs + (size_t)cg * 8 * HWs;
        bf16x8 v8;
#pragma unroll
        for (int c = 0; c < 8; ++c)
            v8[c] = (short)f2bf(img[(size_t)c * HWs + pix]);
        *(bf16x8*)(egocl + ((size_t)b * HWs + pix) * CC + cg * 8) = v8;
    } else {
        int i = (cg * 33 + xb) * 256 + threadIdx.x;
        if (i < 2 * 9 * 32 * 32) {
            int half = i / (9 * 32 * 32);
            int rr   = i % (9 * 32 * 32);
            int tap  = rr / (32 * 32);
            int r2   = rr % (32 * 32);
            int oc   = r2 / 32;
            int ic   = r2 % 32;
            Wp[i] = f2bf(msg_w[(size_t)oc * 576 + (size_t)(half * 32 + ic) * 9 + tap]);
        } else if (i < 2 * 9 * 32 * 32 + 32 * 32) {
            int k = i - 2 * 9 * 32 * 32;
            Wp2[k] = f2bf(mlp_w[k]);     // [d][c] row-major, as stored
        }
    }
}

// read one B-fragment (8 bf16 elems) from padded LDS weight array
__device__ __forceinline__ bf16x8 ldfrag(const unsigned short* __restrict__ wl,
                                         int row, int kblk)
{
    const unsigned short* p = wl + row * WROW + kblk * 8;   // 8B-aligned
    ushort4 u0 = *(const ushort4*)(p);
    ushort4 u1 = *(const ushort4*)(p + 4);
    bf16x8 r;
    r[0] = (short)u0.x; r[1] = (short)u0.y; r[2] = (short)u0.z; r[3] = (short)u0.w;
    r[4] = (short)u1.x; r[5] = (short)u1.y; r[6] = (short)u1.z; r[7] = (short)u1.w;
    return r;
}

// ---- K_fused: per-wave 16-pixel tile; weights LDS-staged once/block; rolling
//      A-prefetch; 6 half-convs + bias + mask*max + skip + mlp MFMA ----
__global__ __launch_bounds__(256) void k_fused(const unsigned short* __restrict__ warpedcl,
                                               const unsigned short* __restrict__ egocl,
                                               const float* __restrict__ maskb,
                                               const unsigned short* __restrict__ Wp,
                                               const unsigned short* __restrict__ Wp2,
                                               const float* __restrict__ msg_b,
                                               const float* __restrict__ mlp_b,
                                               float* __restrict__ out)
{
    __shared__ unsigned short wlds[608 * WROW];   // 43,776 B: rows 0..575 msg, 576..607 mlp
    __shared__ float fl[64][33];                  //  8,448 B

    const int tid  = threadIdx.x;
    const int wv   = tid >> 6;
    const int lane = tid & 63;
    const int lo   = lane & 15;
    const int kblk = lane >> 4;
    const int b    = blockIdx.y;
    const int p0   = blockIdx.x * 64 + wv * 16;
    const int pf   = p0 + lo;
    const int ph   = pf / WW, pw = pf % WW;

    // ---- stage Wp (18432) + Wp2 (1024, contiguous after Wp) into padded LDS ----
#pragma unroll
    for (int k = 0; k < 19; ++k) {
        int g = k * 256 + tid;
        ushort4 u = *(const ushort4*)(Wp + 4 * g);       // coalesced 8B global
        int row = g >> 3, col = (g & 7) * 4;
        *(ushort4*)(wlds + row * WROW + col) = u;        // 8B-aligned ds_write
    }

    // per-tap safe source pixel + validity (overlaps with staging)
    int ps[9];
    unsigned vbits = 0;
#pragma unroll
    for (int tap = 0; tap < 9; ++tap) {
        int dy = tap / 3 - 1, dx = tap % 3 - 1;
        int hh = ph + dy, wwp = pw + dx;
        bool valid = (hh >= 0) && (hh < HH) && (wwp >= 0) && (wwp < WW);
        ps[tap] = valid ? (pf + dy * WW + dx) : pf;
        vbits |= (valid ? 1u : 0u) << tap;
    }
    const bf16x8 zero = {0, 0, 0, 0, 0, 0, 0, 0};

    // issue ego A-frags + all masks early (fly under the barrier)
    bf16x8 afe[9];
    const unsigned short* Ae = egocl + (size_t)b * HWs * CC;
#pragma unroll
    for (int tap = 0; tap < 9; ++tap)
        afe[tap] = *(const bf16x8*)(Ae + (size_t)ps[tap] * CC + kblk * 8);
    float4 mks[LL];
#pragma unroll
    for (int j = 0; j < LL; ++j)
        mks[j] = *(const float4*)(maskb + (size_t)(b * LL + j) * HWs + p0 + kblk * 4);

    __syncthreads();

    // B-frags for warped half from LDS (kept in regs across all 5 j)
    bf16x8 Bw[9][2];
#pragma unroll
    for (int tap = 0; tap < 9; ++tap)
#pragma unroll
        for (int nt = 0; nt < 2; ++nt)
            Bw[tap][nt] = ldfrag(wlds, tap * 32 + nt * 16 + lo, kblk);

    // ego half-conv (+ conv bias); ego B-frags read from LDS on the fly
    f32x4 acce[2] = {};
#pragma unroll
    for (int tap = 0; tap < 9; ++tap) {
        bf16x8 a = ((vbits >> tap) & 1) ? afe[tap] : zero;
#pragma unroll
        for (int nt = 0; nt < 2; ++nt) {
            bf16x8 Be = ldfrag(wlds, 288 + tap * 32 + nt * 16 + lo, kblk);
            acce[nt] = __builtin_amdgcn_mfma_f32_16x16x32_bf16(a, Be, acce[nt], 0, 0, 0);
        }
    }
    {
        float b0 = msg_b[lo], b1 = msg_b[16 + lo];
#pragma unroll
        for (int r = 0; r < 4; ++r) { acce[0][r] += b0; acce[1][r] += b1; }
    }

    // rolling 3-buffer A-prefetch over j (full unroll -> static indices)
    bf16x8 afw[3][9];
#pragma unroll
    for (int jj = 0; jj < 2; ++jj) {
        const unsigned short* Aw = warpedcl + (size_t)(b * LL + jj) * HWs * CC;
#pragma unroll
        for (int tap = 0; tap < 9; ++tap)
            afw[jj][tap] = *(const bf16x8*)(Aw + (size_t)ps[tap] * CC + kblk * 8);
    }

    f32x4 agg[2];
#pragma unroll
    for (int r = 0; r < 4; ++r) { agg[0][r] = -INFINITY; agg[1][r] = -INFINITY; }

#pragma unroll
    for (int j = 0; j < LL; ++j) {
        if (j + 2 < LL) {
            const unsigned short* Aw = warpedcl + (size_t)(b * LL + j + 2) * HWs * CC;
#pragma unroll
            for (int tap = 0; tap < 9; ++tap)
                afw[(j + 2) % 3][tap] = *(const bf16x8*)(Aw + (size_t)ps[tap] * CC + kblk * 8);
        }
        f32x4 acc[2] = {};
#pragma unroll
        for (int tap = 0; tap < 9; ++tap) {
            bf16x8 a = ((vbits >> tap) & 1) ? afw[j % 3][tap] : zero;
#pragma unroll
            for (int nt = 0; nt < 2; ++nt)
                acc[nt] = __builtin_amdgcn_mfma_f32_16x16x32_bf16(a, Bw[tap][nt], acc[nt], 0, 0, 0);
        }
        float mkr[4] = {mks[j].x, mks[j].y, mks[j].z, mks[j].w};
#pragma unroll
        for (int nt = 0; nt < 2; ++nt)
#pragma unroll
            for (int r = 0; r < 4; ++r)
                agg[nt][r] = fmaxf(agg[nt][r], (acc[nt][r] + acce[nt][r]) * mkr[r]);
    }

    // f = agg + skip(egocl bf16) -> per-wave LDS transpose -> mlp MFMA
#pragma unroll
    for (int nt = 0; nt < 2; ++nt)
#pragma unroll
        for (int r = 0; r < 4; ++r) {
            int pixl = kblk * 4 + r;
            float skip = bf2f(egocl[((size_t)b * HWs + p0 + pixl) * CC + nt * 16 + lo]);
            fl[wv * 16 + pixl][nt * 16 + lo] = agg[nt][r] + skip;
        }
    // same-wave LDS read-back (lgkmcnt ordering; no cross-wave sharing)
    bf16x8 Afm;
#pragma unroll
    for (int e = 0; e < 8; ++e)
        Afm[e] = (short)f2bf(fl[wv * 16 + lo][kblk * 8 + e]);

#pragma unroll
    for (int nt2 = 0; nt2 < 2; ++nt2) {
        bf16x8 Bm = ldfrag(wlds, 576 + nt2 * 16 + lo, kblk);
        f32x4 om = {};
        om = __builtin_amdgcn_mfma_f32_16x16x32_bf16(Afm, Bm, om, 0, 0, 0);
        float mb2 = mlp_b[nt2 * 16 + lo];
        int d = nt2 * 16 + lo;
#pragma unroll
        for (int r = 0; r < 4; ++r)
            out[((size_t)b * CC + d) * HWs + p0 + kblk * 4 + r] = om[r] + mb2;
    }
}

extern "C" void kernel_launch(void* const* d_in, const int* in_sizes, int n_in,
                              void* d_out, int out_size, void* d_ws, size_t ws_size,
                              hipStream_t stream)
{
    (void)in_sizes; (void)n_in; (void)out_size; (void)ws_size;
    const float* x     = (const float*)d_in[0];
    // d_in[1] = record_len (unused by reference)
    const float* M     = (const float*)d_in[2];
    const float* msg_w = (const float*)d_in[3];
    const float* msg_b = (const float*)d_in[4];
    const float* mlp_w = (const float*)d_in[5];
    const float* mlp_b = (const float*)d_in[6];
    float* out = (float*)d_out;

    // workspace layout (all segments 16B-aligned; Wp2 contiguous after Wp)
    unsigned short* Wp       = (unsigned short*)d_ws;                    // 18432 bf16
    unsigned short* Wp2      = Wp + 2 * 9 * 32 * 32;                     // 1024 bf16
    unsigned short* warpedcl = Wp2 + 32 * 32;                            // BL*HW*C bf16
    unsigned short* egocl    = warpedcl + (size_t)BL * HWs * CC;         // BB*HW*C bf16
    float*          maskb    = (float*)(egocl + (size_t)BB * HWs * CC);  // BL*HW f32

    {
        k_prep<<<dim3(1716), 256, 0, stream>>>(x, M, msg_w, mlp_w,
                                               warpedcl, egocl, maskb, Wp, Wp2);
    }
    {
        dim3 g(HWs / 64, BB);                // (132, 2)
        k_fused<<<g, 256, 0, stream>>>(warpedcl, egocl, maskb, Wp, Wp2,
                                       msg_b, mlp_b, out);
    }
}